// Round 3
// baseline (1146.453 us; speedup 1.0000x reference)
//
#include <hip/hip_runtime.h>

typedef __bf16 bf16_t;
typedef bf16_t bf16x8 __attribute__((ext_vector_type(8)));
typedef float f32x4 __attribute__((ext_vector_type(4)));
typedef unsigned short u16;

#define P_TOTAL 98304
#define PTS_PER_BATCH 49152
#define PITCH 520   // u16 elements per LDS row (1040 B)

__device__ __forceinline__ u16 f2bs(float f){ bf16_t b=(bf16_t)f; return __builtin_bit_cast(u16,b); }

// ---------- weight transform: (K=512,N=512) fp32 -> MFMA-fragment-linear bf16 ----------
// Layout (per gemm): idx = ((nstrip*16 + kt)*2 + nt)*512 + lane*8 + j
//   value = W[k][n],  n = nstrip*32 + nt*16 + (lane&15),  k = kt*32 + (lane>>4)*8 + j
__global__ void k_wtrans15(const float* __restrict__ lz, const float* __restrict__ f0,
                           const float* __restrict__ f1, u16* __restrict__ dst){
  int kt = blockIdx.x, ns = blockIdx.y, z = blockIdx.z;
  const float* src = (z<5) ? (lz + (size_t)z*262144)
                   : (z<10 ? (f0 + (size_t)(z-5)*262144)
                           : (f1 + (size_t)(z-10)*262144));
  u16* d = dst + (size_t)z*262144 + (size_t)(ns*16 + kt)*1024;
  int l = threadIdx.x;
  int col = ns*32 + (l&15);
  int kr  = kt*32 + (l>>4)*8;
  #pragma unroll
  for (int nt=0;nt<2;nt++){
    bf16x8 o;
    #pragma unroll
    for (int j=0;j<8;j++) o[j] = (bf16_t)src[(size_t)(kr+j)*512 + col + nt*16];
    *(bf16x8*)(d + nt*512 + l*8) = o;
  }
}

// lin_in: (63,512) fp32 -> fragment-linear bf16, K padded to 64 (2 kt chunks)
__global__ void k_wtrans_in(const float* __restrict__ w, u16* __restrict__ dst){
  int kt = blockIdx.x, ns = blockIdx.y;
  u16* d = dst + (size_t)(ns*2 + kt)*1024;
  int l = threadIdx.x;
  int col = ns*32 + (l&15);
  int kr  = kt*32 + (l>>4)*8;
  #pragma unroll
  for (int nt=0;nt<2;nt++){
    bf16x8 o;
    #pragma unroll
    for (int j=0;j<8;j++){
      int k = kr + j;
      o[j] = (k < 63) ? (bf16_t)w[(size_t)k*512 + col + nt*16] : (bf16_t)0.f;
    }
    *(bf16x8*)(d + nt*512 + l*8) = o;
  }
}

// ---------- feature transpose: (B,512,128,128) f32 -> (B,128,128,512) bf16 ----------
__global__ void k_featT(const float* __restrict__ feat, u16* __restrict__ featT){
  int x = threadIdx.x;
  int c8 = blockIdx.x*8;
  int y = blockIdx.y, b = blockIdx.z;
  float v[8];
  #pragma unroll
  for (int j=0;j<8;j++)
    v[j] = feat[(((size_t)(b*512 + c8 + j))*128 + y)*128 + x];
  bf16x8 o;
  #pragma unroll
  for (int j=0;j<8;j++) o[j] = (bf16_t)v[j];
  *(bf16x8*)(featT + (((size_t)(b*128 + y))*128 + x)*512 + c8) = o;
}

// ---------- per-point: geometry + bilinear + positional encoding ----------
__global__ void k_points(const float* __restrict__ world, const float* __restrict__ c2w,
                         const float* __restrict__ kmat, const u16* __restrict__ featT,
                         u16* __restrict__ alignedB, u16* __restrict__ encB){
  int wid = threadIdx.x >> 6, lane = threadIdx.x & 63;
  int gp = blockIdx.x*4 + wid;
  int b = gp / PTS_PER_BATCH;
  const float* wp = world + (size_t)gp*3;
  float px = wp[0], py = wp[1], pz = wp[2];
  const float* cw = c2w + b*16;
  float dx = px - cw[3], dy = py - cw[7], dz = pz - cw[11];
  float cx = cw[0]*dx + cw[4]*dy + cw[8]*dz;
  float cy = cw[1]*dx + cw[5]*dy + cw[9]*dz;
  float cz = cw[2]*dx + cw[6]*dy + cw[10]*dz;
  const float* km = kmat + b*9;
  float u0 = km[0]*cx + km[1]*cy + km[2]*cz;
  float v0 = km[3]*cx + km[4]*cy + km[5]*cz;
  float zz = km[6]*cx + km[7]*cy + km[8]*cz;
  if (fabsf(zz) < 1e-6f) zz = 1e-6f;
  float uu = u0/zz, vv = v0/zz;
  float xf = fminf(fmaxf(uu, 0.f), 127.f);
  float yf = fminf(fmaxf(vv, 0.f), 127.f);
  float x0f = floorf(xf), y0f = floorf(yf);
  int x0 = (int)x0f, y0 = (int)y0f;
  int x1 = min(x0+1,127), y1 = min(y0+1,127);
  float wx = xf - x0f, wy = yf - y0f;
  float w00 = (1.f-wx)*(1.f-wy), w01 = wx*(1.f-wy), w10 = (1.f-wx)*wy, w11 = wx*wy;
  size_t fb = (size_t)b*128*128*512;
  int c8 = lane*8;
  const bf16x8 t00 = *(const bf16x8*)(featT + fb + (size_t)(y0*128+x0)*512 + c8);
  const bf16x8 t01 = *(const bf16x8*)(featT + fb + (size_t)(y0*128+x1)*512 + c8);
  const bf16x8 t10 = *(const bf16x8*)(featT + fb + (size_t)(y1*128+x0)*512 + c8);
  const bf16x8 t11 = *(const bf16x8*)(featT + fb + (size_t)(y1*128+x1)*512 + c8);
  bf16x8 o;
  #pragma unroll
  for (int j=0;j<8;j++){
    float r = (float)t00[j]*w00 + (float)t01[j]*w01 + (float)t10[j]*w10 + (float)t11[j]*w11;
    o[j] = (bf16_t)r;
  }
  *(bf16x8*)(alignedB + (size_t)gp*512 + c8) = o;
  float cam[3] = {cx, cy, cz};
  float e;
  if (lane < 3) e = cam[lane];
  else if (lane < 33){
    int i = (lane-3)/10, f = (lane-3)%10;
    e = sinf(6.2831855f * cam[i] * (float)(1<<f));
  } else if (lane < 63){
    int i = (lane-33)/10, f = (lane-33)%10;
    e = cosf(6.2831855f * cam[i] * (float)(1<<f));
  } else e = 0.f;
  encB[(size_t)gp*64 + lane] = f2bs(e);
}

// ============ fused persistent MLP: 1024 thr (16 waves), M=64/block ============
// Wave grid 2m x 8n: wave w -> mg = w>>3 (m-half [mg*32,mg*32+32)),
//                              ng = w&7  (n-strip [ng*64,ng*64+64)).
// Halves per-wave LDS B-reads vs 1x16 grid (each wave reads only its 32 rows).
// The mg=0/mg=1 waves sharing an ng read the SAME weight stream ~in lockstep ->
// duplicate absorbed by per-CU L1 (32 KB >> one kt window of 4 KB).
// Weights are the MFMA A-operand (fragment-linear contiguous 1KB wave-loads),
// activations from LDS are the B-operand. C[n][m]: lane holds m = bt*16+(l&15),
// reg r holds n = ng*64 + nt*16 + (l>>4)*4 + r -> packed ds_write_b64 relu writes.
// h fp32 resident: h[2][4] = 32 regs; peak live (fc0) ~119 VGPR < 128 cap.

template<int NK>
__device__ __forceinline__ void gemm2(const u16* sB, const u16* __restrict__ Af,
                                      int mg, int fm, int fk8, int l, f32x4 (&acc)[2][4]){
  const u16* ap = Af + l*8;          // this lane's 16B within each 1KB fragment block
  constexpr int NS = NK*1024;        // n-strip (32-col) block stride in u16
  bf16x8 a[2][4];
  #pragma unroll
  for (int d=0; d<2; ++d)
    #pragma unroll
    for (int nt=0; nt<4; ++nt)
      a[d][nt] = *(const bf16x8*)(ap + (nt>>1)*NS + d*1024 + (nt&1)*512);
  const u16* bp = sB + (mg*32 + fm)*PITCH + fk8*8;
  #pragma unroll 1
  for (int kb=0; kb<NK/2-1; ++kb){
    #pragma unroll
    for (int d=0; d<2; ++d){
      const int kt = kb*2 + d;
      bf16x8 bfr[2];
      #pragma unroll
      for (int bt=0; bt<2; ++bt)
        bfr[bt] = *(const bf16x8*)(bp + bt*16*PITCH + kt*32);
      bf16x8 a0 = a[d][0], a1 = a[d][1], a2 = a[d][2], a3 = a[d][3];
      #pragma unroll
      for (int nt=0; nt<4; ++nt)
        a[d][nt] = *(const bf16x8*)(ap + (nt>>1)*NS + (kt+2)*1024 + (nt&1)*512);
      #pragma unroll
      for (int bt=0; bt<2; ++bt){
        acc[bt][0] = __builtin_amdgcn_mfma_f32_16x16x32_bf16(a0, bfr[bt], acc[bt][0], 0,0,0);
        acc[bt][1] = __builtin_amdgcn_mfma_f32_16x16x32_bf16(a1, bfr[bt], acc[bt][1], 0,0,0);
        acc[bt][2] = __builtin_amdgcn_mfma_f32_16x16x32_bf16(a2, bfr[bt], acc[bt][2], 0,0,0);
        acc[bt][3] = __builtin_amdgcn_mfma_f32_16x16x32_bf16(a3, bfr[bt], acc[bt][3], 0,0,0);
      }
    }
  }
  #pragma unroll
  for (int d=0; d<2; ++d){           // tail pair, no prefetch
    const int kt = NK - 2 + d;
    bf16x8 bfr[2];
    #pragma unroll
    for (int bt=0; bt<2; ++bt)
      bfr[bt] = *(const bf16x8*)(bp + bt*16*PITCH + kt*32);
    #pragma unroll
    for (int bt=0; bt<2; ++bt)
      #pragma unroll
      for (int nt=0; nt<4; ++nt)
        acc[bt][nt] = __builtin_amdgcn_mfma_f32_16x16x32_bf16(a[d][nt], bfr[bt], acc[bt][nt], 0,0,0);
  }
}

__device__ __forceinline__ void add_bias2(const float* __restrict__ bias, int wn64, int rq,
                                          f32x4 (&acc)[2][4]){
  #pragma unroll
  for (int nt=0; nt<4; ++nt){
    f32x4 bv = *(const f32x4*)&bias[wn64 + nt*16 + rq];
    #pragma unroll
    for (int bt=0; bt<2; ++bt)
      #pragma unroll
      for (int r=0; r<4; ++r)
        acc[bt][nt][r] += bv[r];
  }
}

// write relu(acc) bf16 into LDS rows m (C[n][m] -> act[m][k=n] layout), packed b64
__device__ __forceinline__ void write_relu2(u16* dst, int mg, int fm, int rq, int wn64,
                                            f32x4 (&acc)[2][4]){
  #pragma unroll
  for (int bt=0; bt<2; ++bt){
    int m = mg*32 + bt*16 + fm;
    #pragma unroll
    for (int nt=0; nt<4; ++nt){
      int kb = wn64 + nt*16 + rq;    // multiple of 4 -> 8B aligned
      u16 p0 = f2bs(fmaxf(acc[bt][nt][0], 0.f));
      u16 p1 = f2bs(fmaxf(acc[bt][nt][1], 0.f));
      u16 p2 = f2bs(fmaxf(acc[bt][nt][2], 0.f));
      u16 p3 = f2bs(fmaxf(acc[bt][nt][3], 0.f));
      uint2 v;
      v.x = (unsigned)p0 | ((unsigned)p1 << 16);
      v.y = (unsigned)p2 | ((unsigned)p3 << 16);
      *(uint2*)&dst[m*PITCH + kb] = v;
    }
  }
}

__global__ __launch_bounds__(1024, 4) void k_net(
    const u16* __restrict__ alignedB, const u16* __restrict__ encB,
    const u16* __restrict__ wtin, const float* __restrict__ b_in,
    const u16* __restrict__ wts, const float* __restrict__ bz,
    const float* __restrict__ b0, const float* __restrict__ b1,
    const float* __restrict__ wout, const float* __restrict__ bout,
    float* __restrict__ out)
{
  __shared__ u16 bufA[64*PITCH];   // aligned (65 KB, persistent)
  __shared__ u16 bufB[64*PITCH];   // activations (65 KB)
  const int t = threadIdx.x, w = t>>6, l = t&63;
  const int m0 = blockIdx.x*64;
  const int mg = w>>3, ng = w&7;
  const int wn64 = ng*64, fm = l&15, fk8 = l>>4, rq = (l>>4)*4;

  // stage aligned[m0:m0+64][0:512] -> bufA
  {
    int m = t>>4, c = t&15;
    #pragma unroll
    for (int j=0;j<4;j++){
      int kc = c*4 + j;
      *(uint4*)&bufA[m*PITCH + kc*8] =
          *(const uint4*)(alignedB + (size_t)(m0+m)*512 + kc*8);
    }
  }
  // stage enc[m0:m0+64][0:64] -> bufB (first 512 thr)
  if (t < 512){
    int m = t>>3, kc = t&7;
    *(uint4*)&bufB[m*PITCH + kc*8] =
        *(const uint4*)(encB + (size_t)(m0+m)*64 + kc*8);
  }
  __syncthreads();

  f32x4 h[2][4] = {};
  gemm2<2>(bufB, wtin + (size_t)ng*4096, mg, fm, fk8, l, h);
  add_bias2(b_in, wn64, rq, h);

  #pragma unroll 1
  for (int i=0;i<5;i++){
    // h += aligned @ Wz + bz   (bufA as B-operand)
    gemm2<16>(bufA, wts + (size_t)i*262144 + (size_t)ng*32768, mg, fm, fk8, l, h);
    add_bias2(bz + i*512, wn64, rq, h);
    __syncthreads();                       // prior bufB readers done
    write_relu2(bufB, mg, fm, rq, wn64, h);    // bufB = relu(h)
    __syncthreads();
    f32x4 acc[2][4] = {};
    gemm2<16>(bufB, wts + (size_t)(5+i)*262144 + (size_t)ng*32768, mg, fm, fk8, l, acc);
    add_bias2(b0 + i*512, wn64, rq, acc);
    __syncthreads();                       // all fc0 reads of bufB done
    write_relu2(bufB, mg, fm, rq, wn64, acc);  // bufB = relu(net)
    __syncthreads();
    gemm2<16>(bufB, wts + (size_t)(10+i)*262144 + (size_t)ng*32768, mg, fm, fk8, l, h);
    add_bias2(b1 + i*512, wn64, rq, h);
  }

  // sigma = exp(relu(h) . wout + bout); per lane: 2 m-cols (bt), 16 n-rows (nt,r)
  float s[2];
  {
    #pragma unroll
    for (int bt=0; bt<2; ++bt) s[bt] = 0.f;
    #pragma unroll
    for (int nt=0; nt<4; ++nt){
      f32x4 wv = *(const f32x4*)&wout[wn64 + nt*16 + rq];
      #pragma unroll
      for (int bt=0; bt<2; ++bt)
        #pragma unroll
        for (int r=0; r<4; ++r)
          s[bt] += fmaxf(h[bt][nt][r], 0.f) * wv[r];
    }
  }
  #pragma unroll
  for (int bt=0; bt<2; ++bt){
    s[bt] += __shfl_xor(s[bt], 16, 64);    // fold the 4 (l>>4) rq-groups
    s[bt] += __shfl_xor(s[bt], 32, 64);
  }
  __syncthreads();                 // all fc1 reads of bufB done; reuse as red[16][32]
  float* red = (float*)bufB;
  if (l < 16){
    #pragma unroll
    for (int bt=0; bt<2; ++bt)
      red[w*32 + bt*16 + l] = s[bt];       // m_local = bt*16 + fm (within mg half)
  }
  __syncthreads();
  if (t < 64){
    int mgo = t>>5, ml = t&31;
    float a = bout[0];
    #pragma unroll
    for (int g=0; g<8; g++) a += red[(mgo*8+g)*32 + ml];
    out[m0 + t] = expf(a);
  }
}

extern "C" void kernel_launch(void* const* d_in, const int* in_sizes, int n_in,
                              void* d_out, int out_size, void* d_ws, size_t ws_size,
                              hipStream_t stream) {
  const float* world = (const float*)d_in[0];
  const float* c2w   = (const float*)d_in[1];
  const float* kmat  = (const float*)d_in[2];
  const float* feat  = (const float*)d_in[3];
  const float* w_in  = (const float*)d_in[4];
  const float* b_in  = (const float*)d_in[5];
  const float* w_z   = (const float*)d_in[6];
  const float* b_z   = (const float*)d_in[7];
  const float* w_f0  = (const float*)d_in[8];
  const float* b_f0  = (const float*)d_in[9];
  const float* w_f1  = (const float*)d_in[10];
  const float* b_f1  = (const float*)d_in[11];
  const float* w_out = (const float*)d_in[12];
  const float* b_out = (const float*)d_in[13];
  float* out = (float*)d_out;
  char* ws = (char*)d_ws;

  size_t off = 0;
  u16* wts   = (u16*)(ws + off); off += (size_t)15*262144*2;       // 15x fragment-linear bf16
  u16* wtin  = (u16*)(ws + off); off += (size_t)512*64*2;          // lin_in fragment-linear bf16
  u16* featT = (u16*)(ws + off); off += (size_t)2*128*128*512*2;   // transposed features
  u16* alignedB = (u16*)(ws + off); off += (size_t)P_TOTAL*512*2;  // sampled features bf16
  u16* encB  = (u16*)(ws + off); off += (size_t)P_TOTAL*64*2;      // positional enc bf16

  k_wtrans15<<<dim3(16,16,15), 64, 0, stream>>>(w_z, w_f0, w_f1, wts);
  k_wtrans_in<<<dim3(2,16,1), 64, 0, stream>>>(w_in, wtin);
  k_featT<<<dim3(64,128,2), 128, 0, stream>>>(feat, featT);
  k_points<<<dim3(P_TOTAL/4), 256, 0, stream>>>(world, c2w, kmat, featT, alignedB, encB);
  k_net<<<dim3(P_TOTAL/64), 1024, 0, stream>>>(alignedB, encB, wtin, b_in, wts,
      b_z, b_f0, b_f1, w_out, b_out, out);
}

// Round 4
// 851.851 us; speedup vs baseline: 1.3458x; 1.3458x over previous
//
#include <hip/hip_runtime.h>

typedef __bf16 bf16_t;
typedef bf16_t bf16x8 __attribute__((ext_vector_type(8)));
typedef float f32x4 __attribute__((ext_vector_type(4)));
typedef unsigned short u16;

#define P_TOTAL 98304
#define PTS_PER_BATCH 49152
#define PITCH 520   // u16 elements per LDS row (1040 B)

__device__ __forceinline__ u16 f2bs(float f){ bf16_t b=(bf16_t)f; return __builtin_bit_cast(u16,b); }

// ---------- weight transform: (K=512,N=512) fp32 -> MFMA-fragment-linear bf16 ----------
// Layout (per gemm): idx = ((nstrip*16 + kt)*2 + nt)*512 + lane*8 + j
//   value = W[k][n],  n = nstrip*32 + nt*16 + (lane&15),  k = kt*32 + (lane>>4)*8 + j
__global__ void k_wtrans15(const float* __restrict__ lz, const float* __restrict__ f0,
                           const float* __restrict__ f1, u16* __restrict__ dst){
  int kt = blockIdx.x, ns = blockIdx.y, z = blockIdx.z;
  const float* src = (z<5) ? (lz + (size_t)z*262144)
                   : (z<10 ? (f0 + (size_t)(z-5)*262144)
                           : (f1 + (size_t)(z-10)*262144));
  u16* d = dst + (size_t)z*262144 + (size_t)(ns*16 + kt)*1024;
  int l = threadIdx.x;
  int col = ns*32 + (l&15);
  int kr  = kt*32 + (l>>4)*8;
  #pragma unroll
  for (int nt=0;nt<2;nt++){
    bf16x8 o;
    #pragma unroll
    for (int j=0;j<8;j++) o[j] = (bf16_t)src[(size_t)(kr+j)*512 + col + nt*16];
    *(bf16x8*)(d + nt*512 + l*8) = o;
  }
}

// lin_in: (63,512) fp32 -> fragment-linear bf16, K padded to 64 (2 kt chunks)
__global__ void k_wtrans_in(const float* __restrict__ w, u16* __restrict__ dst){
  int kt = blockIdx.x, ns = blockIdx.y;
  u16* d = dst + (size_t)(ns*2 + kt)*1024;
  int l = threadIdx.x;
  int col = ns*32 + (l&15);
  int kr  = kt*32 + (l>>4)*8;
  #pragma unroll
  for (int nt=0;nt<2;nt++){
    bf16x8 o;
    #pragma unroll
    for (int j=0;j<8;j++){
      int k = kr + j;
      o[j] = (k < 63) ? (bf16_t)w[(size_t)k*512 + col + nt*16] : (bf16_t)0.f;
    }
    *(bf16x8*)(d + nt*512 + l*8) = o;
  }
}

// ---------- feature transpose: (B,512,128,128) f32 -> (B,128,128,512) bf16 ----------
__global__ void k_featT(const float* __restrict__ feat, u16* __restrict__ featT){
  int x = threadIdx.x;
  int c8 = blockIdx.x*8;
  int y = blockIdx.y, b = blockIdx.z;
  float v[8];
  #pragma unroll
  for (int j=0;j<8;j++)
    v[j] = feat[(((size_t)(b*512 + c8 + j))*128 + y)*128 + x];
  bf16x8 o;
  #pragma unroll
  for (int j=0;j<8;j++) o[j] = (bf16_t)v[j];
  *(bf16x8*)(featT + (((size_t)(b*128 + y))*128 + x)*512 + c8) = o;
}

// ---------- per-point: geometry + bilinear + positional encoding ----------
__global__ void k_points(const float* __restrict__ world, const float* __restrict__ c2w,
                         const float* __restrict__ kmat, const u16* __restrict__ featT,
                         u16* __restrict__ alignedB, u16* __restrict__ encB){
  int wid = threadIdx.x >> 6, lane = threadIdx.x & 63;
  int gp = blockIdx.x*4 + wid;
  int b = gp / PTS_PER_BATCH;
  const float* wp = world + (size_t)gp*3;
  float px = wp[0], py = wp[1], pz = wp[2];
  const float* cw = c2w + b*16;
  float dx = px - cw[3], dy = py - cw[7], dz = pz - cw[11];
  float cx = cw[0]*dx + cw[4]*dy + cw[8]*dz;
  float cy = cw[1]*dx + cw[5]*dy + cw[9]*dz;
  float cz = cw[2]*dx + cw[6]*dy + cw[10]*dz;
  const float* km = kmat + b*9;
  float u0 = km[0]*cx + km[1]*cy + km[2]*cz;
  float v0 = km[3]*cx + km[4]*cy + km[5]*cz;
  float zz = km[6]*cx + km[7]*cy + km[8]*cz;
  if (fabsf(zz) < 1e-6f) zz = 1e-6f;
  float uu = u0/zz, vv = v0/zz;
  float xf = fminf(fmaxf(uu, 0.f), 127.f);
  float yf = fminf(fmaxf(vv, 0.f), 127.f);
  float x0f = floorf(xf), y0f = floorf(yf);
  int x0 = (int)x0f, y0 = (int)y0f;
  int x1 = min(x0+1,127), y1 = min(y0+1,127);
  float wx = xf - x0f, wy = yf - y0f;
  float w00 = (1.f-wx)*(1.f-wy), w01 = wx*(1.f-wy), w10 = (1.f-wx)*wy, w11 = wx*wy;
  size_t fb = (size_t)b*128*128*512;
  int c8 = lane*8;
  const bf16x8 t00 = *(const bf16x8*)(featT + fb + (size_t)(y0*128+x0)*512 + c8);
  const bf16x8 t01 = *(const bf16x8*)(featT + fb + (size_t)(y0*128+x1)*512 + c8);
  const bf16x8 t10 = *(const bf16x8*)(featT + fb + (size_t)(y1*128+x0)*512 + c8);
  const bf16x8 t11 = *(const bf16x8*)(featT + fb + (size_t)(y1*128+x1)*512 + c8);
  bf16x8 o;
  #pragma unroll
  for (int j=0;j<8;j++){
    float r = (float)t00[j]*w00 + (float)t01[j]*w01 + (float)t10[j]*w10 + (float)t11[j]*w11;
    o[j] = (bf16_t)r;
  }
  *(bf16x8*)(alignedB + (size_t)gp*512 + c8) = o;
  float cam[3] = {cx, cy, cz};
  float e;
  if (lane < 3) e = cam[lane];
  else if (lane < 33){
    int i = (lane-3)/10, f = (lane-3)%10;
    e = sinf(6.2831855f * cam[i] * (float)(1<<f));
  } else if (lane < 63){
    int i = (lane-33)/10, f = (lane-33)%10;
    e = cosf(6.2831855f * cam[i] * (float)(1<<f));
  } else e = 0.f;
  encB[(size_t)gp*64 + lane] = f2bs(e);
}

// ============ fused persistent MLP: 512 thr (8 waves), M=64/block ============
// Wave w owns n-strip [w*64, w*64+64). Each weight element loaded exactly ONCE
// per block (no duplication — round-3 lesson), and per-block LDS B-read traffic
// HALVES vs 16x32n waves: 8 waves x 64KB = 512KB/gemm (was 1MB). Each
// ds_read_b128 B-fragment now feeds 4 MFMAs (was 2) -> VALU/LDS per MFMA halves.
// Weights are the MFMA A-operand (fragment-linear contiguous 1KB wave-loads),
// activations from LDS are the B-operand. C[n][m]: lane holds m = bt*16+(l&15),
// reg r holds n = w*64 + nt*16 + (l>>4)*4 + r -> packed ds_write_b64 relu writes.
// h fp32 resident h[4][4]=64 regs; peak live (fc0) ~200 VGPR, fine at 2 waves/SIMD.

template<int NK>
__device__ __forceinline__ void gemm2(const u16* sB, const u16* __restrict__ Af,
                                      int fm, int fk8, int l, f32x4 (&acc)[4][4]){
  const u16* ap = Af + l*8;          // this lane's 16B within each 1KB fragment block
  constexpr int NS = NK*1024;        // n-strip (32-col) block stride in u16
  bf16x8 a[2][4];
  #pragma unroll
  for (int d=0; d<2; ++d)
    #pragma unroll
    for (int nt=0; nt<4; ++nt)
      a[d][nt] = *(const bf16x8*)(ap + (nt>>1)*NS + d*1024 + (nt&1)*512);
  const u16* bp = sB + fm*PITCH + fk8*8;
  #pragma unroll 1
  for (int kb=0; kb<NK/2-1; ++kb){
    #pragma unroll
    for (int d=0; d<2; ++d){
      const int kt = kb*2 + d;
      bf16x8 bfr[4];
      #pragma unroll
      for (int bt=0; bt<4; ++bt)
        bfr[bt] = *(const bf16x8*)(bp + bt*16*PITCH + kt*32);
      bf16x8 a0 = a[d][0], a1 = a[d][1], a2 = a[d][2], a3 = a[d][3];
      #pragma unroll
      for (int nt=0; nt<4; ++nt)
        a[d][nt] = *(const bf16x8*)(ap + (nt>>1)*NS + (kt+2)*1024 + (nt&1)*512);
      #pragma unroll
      for (int bt=0; bt<4; ++bt){
        acc[bt][0] = __builtin_amdgcn_mfma_f32_16x16x32_bf16(a0, bfr[bt], acc[bt][0], 0,0,0);
        acc[bt][1] = __builtin_amdgcn_mfma_f32_16x16x32_bf16(a1, bfr[bt], acc[bt][1], 0,0,0);
        acc[bt][2] = __builtin_amdgcn_mfma_f32_16x16x32_bf16(a2, bfr[bt], acc[bt][2], 0,0,0);
        acc[bt][3] = __builtin_amdgcn_mfma_f32_16x16x32_bf16(a3, bfr[bt], acc[bt][3], 0,0,0);
      }
    }
  }
  #pragma unroll
  for (int d=0; d<2; ++d){           // tail pair, no prefetch
    const int kt = NK - 2 + d;
    bf16x8 bfr[4];
    #pragma unroll
    for (int bt=0; bt<4; ++bt)
      bfr[bt] = *(const bf16x8*)(bp + bt*16*PITCH + kt*32);
    #pragma unroll
    for (int bt=0; bt<4; ++bt)
      #pragma unroll
      for (int nt=0; nt<4; ++nt)
        acc[bt][nt] = __builtin_amdgcn_mfma_f32_16x16x32_bf16(a[d][nt], bfr[bt], acc[bt][nt], 0,0,0);
  }
}

__device__ __forceinline__ void add_bias2(const float* __restrict__ bias, int wn64, int rq,
                                          f32x4 (&acc)[4][4]){
  #pragma unroll
  for (int nt=0; nt<4; ++nt){
    f32x4 bv = *(const f32x4*)&bias[wn64 + nt*16 + rq];
    #pragma unroll
    for (int bt=0; bt<4; ++bt)
      #pragma unroll
      for (int r=0; r<4; ++r)
        acc[bt][nt][r] += bv[r];
  }
}

// write relu(acc) bf16 into LDS rows m (C[n][m] -> act[m][k=n] layout), packed b64
__device__ __forceinline__ void write_relu2(u16* dst, int fm, int rq, int wn64,
                                            f32x4 (&acc)[4][4]){
  #pragma unroll
  for (int bt=0; bt<4; ++bt){
    int m = bt*16 + fm;
    #pragma unroll
    for (int nt=0; nt<4; ++nt){
      int kb = wn64 + nt*16 + rq;    // multiple of 4 -> 8B aligned
      u16 p0 = f2bs(fmaxf(acc[bt][nt][0], 0.f));
      u16 p1 = f2bs(fmaxf(acc[bt][nt][1], 0.f));
      u16 p2 = f2bs(fmaxf(acc[bt][nt][2], 0.f));
      u16 p3 = f2bs(fmaxf(acc[bt][nt][3], 0.f));
      uint2 v;
      v.x = (unsigned)p0 | ((unsigned)p1 << 16);
      v.y = (unsigned)p2 | ((unsigned)p3 << 16);
      *(uint2*)&dst[m*PITCH + kb] = v;
    }
  }
}

__global__ __launch_bounds__(512, 2) void k_net(
    const u16* __restrict__ alignedB, const u16* __restrict__ encB,
    const u16* __restrict__ wtin, const float* __restrict__ b_in,
    const u16* __restrict__ wts, const float* __restrict__ bz,
    const float* __restrict__ b0, const float* __restrict__ b1,
    const float* __restrict__ wout, const float* __restrict__ bout,
    float* __restrict__ out)
{
  __shared__ u16 bufA[64*PITCH];   // aligned (65 KB, persistent)
  __shared__ u16 bufB[64*PITCH];   // activations (65 KB)
  const int t = threadIdx.x, w = t>>6, l = t&63;
  const int m0 = blockIdx.x*64;
  const int wn64 = w*64, fm = l&15, fk8 = l>>4, rq = (l>>4)*4;

  // stage aligned[m0:m0+64][0:512] -> bufA (512 thr x 8 x 16B)
  {
    int m = t>>3, c = t&7;
    #pragma unroll
    for (int j=0;j<8;j++){
      int kc = c + j*8;             // 0..63 covers all 512 columns
      *(uint4*)&bufA[m*PITCH + kc*8] =
          *(const uint4*)(alignedB + (size_t)(m0+m)*512 + kc*8);
    }
  }
  // stage enc[m0:m0+64][0:64] -> bufB (one pass)
  {
    int m = t>>3, kc = t&7;
    *(uint4*)&bufB[m*PITCH + kc*8] =
        *(const uint4*)(encB + (size_t)(m0+m)*64 + kc*8);
  }
  __syncthreads();

  f32x4 h[4][4] = {};
  gemm2<2>(bufB, wtin + (size_t)w*4096, fm, fk8, l, h);
  add_bias2(b_in, wn64, rq, h);

  #pragma unroll 1
  for (int i=0;i<5;i++){
    // h += aligned @ Wz + bz   (bufA as B-operand)
    gemm2<16>(bufA, wts + (size_t)i*262144 + (size_t)w*32768, fm, fk8, l, h);
    add_bias2(bz + i*512, wn64, rq, h);
    __syncthreads();                       // prior bufB readers done
    write_relu2(bufB, fm, rq, wn64, h);    // bufB = relu(h)
    __syncthreads();
    f32x4 acc[4][4] = {};
    gemm2<16>(bufB, wts + (size_t)(5+i)*262144 + (size_t)w*32768, fm, fk8, l, acc);
    add_bias2(b0 + i*512, wn64, rq, acc);
    __syncthreads();                       // all fc0 reads of bufB done
    write_relu2(bufB, fm, rq, wn64, acc);  // bufB = relu(net)
    __syncthreads();
    gemm2<16>(bufB, wts + (size_t)(10+i)*262144 + (size_t)w*32768, fm, fk8, l, h);
    add_bias2(b1 + i*512, wn64, rq, h);
  }

  // sigma = exp(relu(h) . wout + bout); per lane: 4 m-cols (bt), 16 n-rows (nt,r)
  float s[4];
  {
    #pragma unroll
    for (int bt=0; bt<4; ++bt) s[bt] = 0.f;
    #pragma unroll
    for (int nt=0; nt<4; ++nt){
      f32x4 wv = *(const f32x4*)&wout[wn64 + nt*16 + rq];
      #pragma unroll
      for (int bt=0; bt<4; ++bt)
        #pragma unroll
        for (int r=0; r<4; ++r)
          s[bt] += fmaxf(h[bt][nt][r], 0.f) * wv[r];
    }
  }
  #pragma unroll
  for (int bt=0; bt<4; ++bt){
    s[bt] += __shfl_xor(s[bt], 16, 64);    // fold the 4 (l>>4) rq-groups
    s[bt] += __shfl_xor(s[bt], 32, 64);
  }
  __syncthreads();                 // all fc1 reads of bufB done; reuse as red[8][64]
  float* red = (float*)bufB;
  if (l < 16){
    #pragma unroll
    for (int bt=0; bt<4; ++bt)
      red[w*64 + bt*16 + l] = s[bt];
  }
  __syncthreads();
  if (t < 64){
    float a = bout[0];
    #pragma unroll
    for (int wv=0; wv<8; wv++) a += red[wv*64 + t];
    out[m0 + t] = expf(a);
  }
}

extern "C" void kernel_launch(void* const* d_in, const int* in_sizes, int n_in,
                              void* d_out, int out_size, void* d_ws, size_t ws_size,
                              hipStream_t stream) {
  const float* world = (const float*)d_in[0];
  const float* c2w   = (const float*)d_in[1];
  const float* kmat  = (const float*)d_in[2];
  const float* feat  = (const float*)d_in[3];
  const float* w_in  = (const float*)d_in[4];
  const float* b_in  = (const float*)d_in[5];
  const float* w_z   = (const float*)d_in[6];
  const float* b_z   = (const float*)d_in[7];
  const float* w_f0  = (const float*)d_in[8];
  const float* b_f0  = (const float*)d_in[9];
  const float* w_f1  = (const float*)d_in[10];
  const float* b_f1  = (const float*)d_in[11];
  const float* w_out = (const float*)d_in[12];
  const float* b_out = (const float*)d_in[13];
  float* out = (float*)d_out;
  char* ws = (char*)d_ws;

  size_t off = 0;
  u16* wts   = (u16*)(ws + off); off += (size_t)15*262144*2;       // 15x fragment-linear bf16
  u16* wtin  = (u16*)(ws + off); off += (size_t)512*64*2;          // lin_in fragment-linear bf16
  u16* featT = (u16*)(ws + off); off += (size_t)2*128*128*512*2;   // transposed features
  u16* alignedB = (u16*)(ws + off); off += (size_t)P_TOTAL*512*2;  // sampled features bf16
  u16* encB  = (u16*)(ws + off); off += (size_t)P_TOTAL*64*2;      // positional enc bf16

  k_wtrans15<<<dim3(16,16,15), 64, 0, stream>>>(w_z, w_f0, w_f1, wts);
  k_wtrans_in<<<dim3(2,16,1), 64, 0, stream>>>(w_in, wtin);
  k_featT<<<dim3(64,128,2), 128, 0, stream>>>(feat, featT);
  k_points<<<dim3(P_TOTAL/4), 256, 0, stream>>>(world, c2w, kmat, featT, alignedB, encB);
  k_net<<<dim3(P_TOTAL/64), 512, 0, stream>>>(alignedB, encB, wtin, b_in, wts,
      b_z, b_f0, b_f1, w_out, b_out, out);
}

// Round 5
// 837.334 us; speedup vs baseline: 1.3692x; 1.0173x over previous
//
#include <hip/hip_runtime.h>

typedef __bf16 bf16_t;
typedef bf16_t bf16x8 __attribute__((ext_vector_type(8)));
typedef float f32x4 __attribute__((ext_vector_type(4)));
typedef unsigned short u16;

#define P_TOTAL 98304
#define PTS_PER_BATCH 49152
#define PITCH 520   // u16 elements per LDS row (1040 B)

__device__ __forceinline__ u16 f2bs(float f){ bf16_t b=(bf16_t)f; return __builtin_bit_cast(u16,b); }

// lgkm-only barrier: preserves all LDS hazards (ds reads+writes are lgkm-counted)
// but does NOT drain vmcnt -> cross-phase weight prefetch stays in flight.
__device__ __forceinline__ void bar_lds(){
  asm volatile("s_waitcnt lgkmcnt(0)" ::: "memory");
  __builtin_amdgcn_s_barrier();
  __builtin_amdgcn_sched_barrier(0);
}

// ---------- weight transform: (K=512,N=512) fp32 -> MFMA-fragment-linear bf16 ----------
// Layout (per gemm): idx = ((nstrip*16 + kt)*2 + nt)*512 + lane*8 + j
//   value = W[k][n],  n = nstrip*32 + nt*16 + (lane&15),  k = kt*32 + (lane>>4)*8 + j
__global__ void k_wtrans15(const float* __restrict__ lz, const float* __restrict__ f0,
                           const float* __restrict__ f1, u16* __restrict__ dst){
  int kt = blockIdx.x, ns = blockIdx.y, z = blockIdx.z;
  const float* src = (z<5) ? (lz + (size_t)z*262144)
                   : (z<10 ? (f0 + (size_t)(z-5)*262144)
                           : (f1 + (size_t)(z-10)*262144));
  u16* d = dst + (size_t)z*262144 + (size_t)(ns*16 + kt)*1024;
  int l = threadIdx.x;
  int col = ns*32 + (l&15);
  int kr  = kt*32 + (l>>4)*8;
  #pragma unroll
  for (int nt=0;nt<2;nt++){
    bf16x8 o;
    #pragma unroll
    for (int j=0;j<8;j++) o[j] = (bf16_t)src[(size_t)(kr+j)*512 + col + nt*16];
    *(bf16x8*)(d + nt*512 + l*8) = o;
  }
}

// lin_in: (63,512) fp32 -> fragment-linear bf16, K padded to 64 (2 kt chunks)
__global__ void k_wtrans_in(const float* __restrict__ w, u16* __restrict__ dst){
  int kt = blockIdx.x, ns = blockIdx.y;
  u16* d = dst + (size_t)(ns*2 + kt)*1024;
  int l = threadIdx.x;
  int col = ns*32 + (l&15);
  int kr  = kt*32 + (l>>4)*8;
  #pragma unroll
  for (int nt=0;nt<2;nt++){
    bf16x8 o;
    #pragma unroll
    for (int j=0;j<8;j++){
      int k = kr + j;
      o[j] = (k < 63) ? (bf16_t)w[(size_t)k*512 + col + nt*16] : (bf16_t)0.f;
    }
    *(bf16x8*)(d + nt*512 + l*8) = o;
  }
}

// ---------- feature transpose: (B,512,128,128) f32 -> (B,128,128,512) bf16 ----------
__global__ void k_featT(const float* __restrict__ feat, u16* __restrict__ featT){
  int x = threadIdx.x;
  int c8 = blockIdx.x*8;
  int y = blockIdx.y, b = blockIdx.z;
  float v[8];
  #pragma unroll
  for (int j=0;j<8;j++)
    v[j] = feat[(((size_t)(b*512 + c8 + j))*128 + y)*128 + x];
  bf16x8 o;
  #pragma unroll
  for (int j=0;j<8;j++) o[j] = (bf16_t)v[j];
  *(bf16x8*)(featT + (((size_t)(b*128 + y))*128 + x)*512 + c8) = o;
}

// ---------- per-point: geometry + bilinear + positional encoding ----------
__global__ void k_points(const float* __restrict__ world, const float* __restrict__ c2w,
                         const float* __restrict__ kmat, const u16* __restrict__ featT,
                         u16* __restrict__ alignedB, u16* __restrict__ encB){
  int wid = threadIdx.x >> 6, lane = threadIdx.x & 63;
  int gp = blockIdx.x*4 + wid;
  int b = gp / PTS_PER_BATCH;
  const float* wp = world + (size_t)gp*3;
  float px = wp[0], py = wp[1], pz = wp[2];
  const float* cw = c2w + b*16;
  float dx = px - cw[3], dy = py - cw[7], dz = pz - cw[11];
  float cx = cw[0]*dx + cw[4]*dy + cw[8]*dz;
  float cy = cw[1]*dx + cw[5]*dy + cw[9]*dz;
  float cz = cw[2]*dx + cw[6]*dy + cw[10]*dz;
  const float* km = kmat + b*9;
  float u0 = km[0]*cx + km[1]*cy + km[2]*cz;
  float v0 = km[3]*cx + km[4]*cy + km[5]*cz;
  float zz = km[6]*cx + km[7]*cy + km[8]*cz;
  if (fabsf(zz) < 1e-6f) zz = 1e-6f;
  float uu = u0/zz, vv = v0/zz;
  float xf = fminf(fmaxf(uu, 0.f), 127.f);
  float yf = fminf(fmaxf(vv, 0.f), 127.f);
  float x0f = floorf(xf), y0f = floorf(yf);
  int x0 = (int)x0f, y0 = (int)y0f;
  int x1 = min(x0+1,127), y1 = min(y0+1,127);
  float wx = xf - x0f, wy = yf - y0f;
  float w00 = (1.f-wx)*(1.f-wy), w01 = wx*(1.f-wy), w10 = (1.f-wx)*wy, w11 = wx*wy;
  size_t fb = (size_t)b*128*128*512;
  int c8 = lane*8;
  const bf16x8 t00 = *(const bf16x8*)(featT + fb + (size_t)(y0*128+x0)*512 + c8);
  const bf16x8 t01 = *(const bf16x8*)(featT + fb + (size_t)(y0*128+x1)*512 + c8);
  const bf16x8 t10 = *(const bf16x8*)(featT + fb + (size_t)(y1*128+x0)*512 + c8);
  const bf16x8 t11 = *(const bf16x8*)(featT + fb + (size_t)(y1*128+x1)*512 + c8);
  bf16x8 o;
  #pragma unroll
  for (int j=0;j<8;j++){
    float r = (float)t00[j]*w00 + (float)t01[j]*w01 + (float)t10[j]*w10 + (float)t11[j]*w11;
    o[j] = (bf16_t)r;
  }
  *(bf16x8*)(alignedB + (size_t)gp*512 + c8) = o;
  float cam[3] = {cx, cy, cz};
  float e;
  if (lane < 3) e = cam[lane];
  else if (lane < 33){
    int i = (lane-3)/10, f = (lane-3)%10;
    e = sinf(6.2831855f * cam[i] * (float)(1<<f));
  } else if (lane < 63){
    int i = (lane-33)/10, f = (lane-33)%10;
    e = cosf(6.2831855f * cam[i] * (float)(1<<f));
  } else e = 0.f;
  encB[(size_t)gp*64 + lane] = f2bs(e);
}

// ============ fused persistent MLP: 512 thr (8 waves), M=64/block ============
// Wave w owns n-strip [w*64, w*64+64). Latency-hiding version of round-4:
//  (1) B-fragment (LDS) double-buffer: br[kt+1] issued before kt's MFMAs ->
//      removes the per-kt ~120cy ds_read->MFMA bubble.
//  (2) Cross-phase weight prefetch: each gemm's tail loads the NEXT gemm's
//      first 2 kt of A-fragments; barriers are lgkm-only (bar_lds) so these
//      global loads stay in flight across phase boundaries (counted-vmcnt idea).
// Weights = MFMA A-operand (fragment-linear 1KB wave-loads), activations (LDS)
// = B-operand. C[n][m]: lane holds m = bt*16+(l&15), reg r holds
// n = w*64 + nt*16 + (l>>4)*4 + r -> packed ds_write_b64 relu writes.

#define MFMA_BF16 __builtin_amdgcn_mfma_f32_16x16x32_bf16

template<int NK>
__device__ __forceinline__ void gemm2(const u16* sB, const u16* __restrict__ apS,
                                      const u16* __restrict__ apN,
                                      int fm, int fk8, f32x4 (&acc)[4][4], bf16x8 (&a)[2][4]){
  // entry: a[d] holds A-fragments for kt=d (d=0,1) of THIS phase (may be in flight)
  const u16* bp = sB + fm*PITCH + fk8*8;
  bf16x8 br[2][4];
  #pragma unroll
  for (int bt=0; bt<4; ++bt) br[0][bt] = *(const bf16x8*)(bp + bt*16*PITCH);
  #pragma unroll 1
  for (int kb=0; kb<NK/2-1; ++kb){
    #pragma unroll
    for (int d=0; d<2; ++d){
      const int kt = kb*2 + d;
      // prefetch B-fragments for kt+1 (opposite parity slot -> no copy of br[d] needed)
      #pragma unroll
      for (int bt=0; bt<4; ++bt)
        br[d^1][bt] = *(const bf16x8*)(bp + bt*16*PITCH + (kt+1)*32);
      // copy A-fragments (slot d gets overwritten by the kt+2 prefetch)
      bf16x8 ac0=a[d][0], ac1=a[d][1], ac2=a[d][2], ac3=a[d][3];
      #pragma unroll
      for (int nt=0; nt<4; ++nt)
        a[d][nt] = *(const bf16x8*)(apS + (nt>>1)*(NK*1024) + (kt+2)*1024 + (nt&1)*512);
      #pragma unroll
      for (int bt=0; bt<4; ++bt){
        acc[bt][0] = MFMA_BF16(ac0, br[d][bt], acc[bt][0], 0,0,0);
        acc[bt][1] = MFMA_BF16(ac1, br[d][bt], acc[bt][1], 0,0,0);
        acc[bt][2] = MFMA_BF16(ac2, br[d][bt], acc[bt][2], 0,0,0);
        acc[bt][3] = MFMA_BF16(ac3, br[d][bt], acc[bt][3], 0,0,0);
      }
    }
  }
  // tail: kt = NK-2, NK-1; A-prefetch targets the NEXT phase (kt'=0,1; NK'=16 layout)
  #pragma unroll
  for (int d=0; d<2; ++d){
    if (d == 0){
      #pragma unroll
      for (int bt=0; bt<4; ++bt)
        br[1][bt] = *(const bf16x8*)(bp + bt*16*PITCH + (NK-1)*32);
    }
    bf16x8 ac0=a[d][0], ac1=a[d][1], ac2=a[d][2], ac3=a[d][3];
    #pragma unroll
    for (int nt=0; nt<4; ++nt)
      a[d][nt] = *(const bf16x8*)(apN + (nt>>1)*16384 + d*1024 + (nt&1)*512);
    #pragma unroll
    for (int bt=0; bt<4; ++bt){
      acc[bt][0] = MFMA_BF16(ac0, br[d][bt], acc[bt][0], 0,0,0);
      acc[bt][1] = MFMA_BF16(ac1, br[d][bt], acc[bt][1], 0,0,0);
      acc[bt][2] = MFMA_BF16(ac2, br[d][bt], acc[bt][2], 0,0,0);
      acc[bt][3] = MFMA_BF16(ac3, br[d][bt], acc[bt][3], 0,0,0);
    }
  }
}

__device__ __forceinline__ void add_bias2(const float* __restrict__ bias, int wn64, int rq,
                                          f32x4 (&acc)[4][4]){
  #pragma unroll
  for (int nt=0; nt<4; ++nt){
    f32x4 bv = *(const f32x4*)&bias[wn64 + nt*16 + rq];
    #pragma unroll
    for (int bt=0; bt<4; ++bt)
      #pragma unroll
      for (int r=0; r<4; ++r)
        acc[bt][nt][r] += bv[r];
  }
}

// write relu(acc) bf16 into LDS rows m (C[n][m] -> act[m][k=n] layout), packed b64
__device__ __forceinline__ void write_relu2(u16* dst, int fm, int rq, int wn64,
                                            f32x4 (&acc)[4][4]){
  #pragma unroll
  for (int bt=0; bt<4; ++bt){
    int m = bt*16 + fm;
    #pragma unroll
    for (int nt=0; nt<4; ++nt){
      int kb = wn64 + nt*16 + rq;    // multiple of 4 -> 8B aligned
      u16 p0 = f2bs(fmaxf(acc[bt][nt][0], 0.f));
      u16 p1 = f2bs(fmaxf(acc[bt][nt][1], 0.f));
      u16 p2 = f2bs(fmaxf(acc[bt][nt][2], 0.f));
      u16 p3 = f2bs(fmaxf(acc[bt][nt][3], 0.f));
      uint2 v;
      v.x = (unsigned)p0 | ((unsigned)p1 << 16);
      v.y = (unsigned)p2 | ((unsigned)p3 << 16);
      *(uint2*)&dst[m*PITCH + kb] = v;
    }
  }
}

__global__ __launch_bounds__(512, 2) void k_net(
    const u16* __restrict__ alignedB, const u16* __restrict__ encB,
    const u16* __restrict__ wtin, const float* __restrict__ b_in,
    const u16* __restrict__ wts, const float* __restrict__ bz,
    const float* __restrict__ b0, const float* __restrict__ b1,
    const float* __restrict__ wout, const float* __restrict__ bout,
    float* __restrict__ out)
{
  __shared__ u16 bufA[64*PITCH];   // aligned (65 KB, persistent)
  __shared__ u16 bufB[64*PITCH];   // activations (65 KB)
  const int t = threadIdx.x, w = t>>6, l = t&63;
  const int m0 = blockIdx.x*64;
  const int wn64 = w*64, fm = l&15, fk8 = l>>4, rq = (l>>4)*4;

  // preload A-fragments for the enc-gemm (overlaps the staging loads below)
  const u16* apE = wtin + (size_t)w*4096 + l*8;
  bf16x8 afr[2][4];
  #pragma unroll
  for (int d=0; d<2; ++d)
    #pragma unroll
    for (int nt=0; nt<4; ++nt)
      afr[d][nt] = *(const bf16x8*)(apE + (nt>>1)*2048 + d*1024 + (nt&1)*512);

  // stage aligned[m0:m0+64][0:512] -> bufA (512 thr x 8 x 16B)
  {
    int m = t>>3, c = t&7;
    #pragma unroll
    for (int j=0;j<8;j++){
      int kc = c + j*8;             // 0..63 covers all 512 columns
      *(uint4*)&bufA[m*PITCH + kc*8] =
          *(const uint4*)(alignedB + (size_t)(m0+m)*512 + kc*8);
    }
  }
  // stage enc[m0:m0+64][0:64] -> bufB (one pass)
  {
    int m = t>>3, kc = t&7;
    *(uint4*)&bufB[m*PITCH + kc*8] =
        *(const uint4*)(encB + (size_t)(m0+m)*64 + kc*8);
  }
  bar_lds();

  const u16* apz0 = wts + (size_t)w*32768 + l*8;
  f32x4 h[4][4] = {};
  gemm2<2>(bufB, apE, apz0, fm, fk8, h, afr);
  add_bias2(b_in, wn64, rq, h);

  #pragma unroll 1
  for (int i=0;i<5;i++){
    const u16* apz  = wts + (size_t)i*262144      + (size_t)w*32768 + l*8;
    const u16* apf0 = wts + (size_t)(5+i)*262144  + (size_t)w*32768 + l*8;
    const u16* apf1 = wts + (size_t)(10+i)*262144 + (size_t)w*32768 + l*8;
    const u16* apzn = (i<4) ? (wts + (size_t)(i+1)*262144 + (size_t)w*32768 + l*8) : apE;

    // h += aligned @ Wz + bz   (bufA as B-operand); tail prefetches fc0 weights
    gemm2<16>(bufA, apz, apf0, fm, fk8, h, afr);
    add_bias2(bz + i*512, wn64, rq, h);
    bar_lds();                             // prior bufB readers done
    write_relu2(bufB, fm, rq, wn64, h);    // bufB = relu(h)
    bar_lds();
    f32x4 acc[4][4] = {};
    gemm2<16>(bufB, apf0, apf1, fm, fk8, acc, afr);
    add_bias2(b0 + i*512, wn64, rq, acc);
    bar_lds();                             // all fc0 reads of bufB done
    write_relu2(bufB, fm, rq, wn64, acc);  // bufB = relu(net)
    bar_lds();
    gemm2<16>(bufB, apf1, apzn, fm, fk8, h, afr);
    add_bias2(b1 + i*512, wn64, rq, h);
  }

  // sigma = exp(relu(h) . wout + bout); per lane: 4 m-cols (bt), 16 n-rows (nt,r)
  float s[4];
  {
    #pragma unroll
    for (int bt=0; bt<4; ++bt) s[bt] = 0.f;
    #pragma unroll
    for (int nt=0; nt<4; ++nt){
      f32x4 wv = *(const f32x4*)&wout[wn64 + nt*16 + rq];
      #pragma unroll
      for (int bt=0; bt<4; ++bt)
        #pragma unroll
        for (int r=0; r<4; ++r)
          s[bt] += fmaxf(h[bt][nt][r], 0.f) * wv[r];
    }
  }
  #pragma unroll
  for (int bt=0; bt<4; ++bt){
    s[bt] += __shfl_xor(s[bt], 16, 64);    // fold the 4 (l>>4) rq-groups
    s[bt] += __shfl_xor(s[bt], 32, 64);
  }
  bar_lds();                       // all fc1 reads of bufB done; reuse as red[8][64]
  float* red = (float*)bufB;
  if (l < 16){
    #pragma unroll
    for (int bt=0; bt<4; ++bt)
      red[w*64 + bt*16 + l] = s[bt];
  }
  bar_lds();
  if (t < 64){
    float a = bout[0];
    #pragma unroll
    for (int wv=0; wv<8; wv++) a += red[wv*64 + t];
    out[m0 + t] = expf(a);
  }
}

extern "C" void kernel_launch(void* const* d_in, const int* in_sizes, int n_in,
                              void* d_out, int out_size, void* d_ws, size_t ws_size,
                              hipStream_t stream) {
  const float* world = (const float*)d_in[0];
  const float* c2w   = (const float*)d_in[1];
  const float* kmat  = (const float*)d_in[2];
  const float* feat  = (const float*)d_in[3];
  const float* w_in  = (const float*)d_in[4];
  const float* b_in  = (const float*)d_in[5];
  const float* w_z   = (const float*)d_in[6];
  const float* b_z   = (const float*)d_in[7];
  const float* w_f0  = (const float*)d_in[8];
  const float* b_f0  = (const float*)d_in[9];
  const float* w_f1  = (const float*)d_in[10];
  const float* b_f1  = (const float*)d_in[11];
  const float* w_out = (const float*)d_in[12];
  const float* b_out = (const float*)d_in[13];
  float* out = (float*)d_out;
  char* ws = (char*)d_ws;

  size_t off = 0;
  u16* wts   = (u16*)(ws + off); off += (size_t)15*262144*2;       // 15x fragment-linear bf16
  u16* wtin  = (u16*)(ws + off); off += (size_t)512*64*2;          // lin_in fragment-linear bf16
  u16* featT = (u16*)(ws + off); off += (size_t)2*128*128*512*2;   // transposed features
  u16* alignedB = (u16*)(ws + off); off += (size_t)P_TOTAL*512*2;  // sampled features bf16
  u16* encB  = (u16*)(ws + off); off += (size_t)P_TOTAL*64*2;      // positional enc bf16

  k_wtrans15<<<dim3(16,16,15), 64, 0, stream>>>(w_z, w_f0, w_f1, wts);
  k_wtrans_in<<<dim3(2,16,1), 64, 0, stream>>>(w_in, wtin);
  k_featT<<<dim3(64,128,2), 128, 0, stream>>>(feat, featT);
  k_points<<<dim3(P_TOTAL/4), 256, 0, stream>>>(world, c2w, kmat, featT, alignedB, encB);
  k_net<<<dim3(P_TOTAL/64), 512, 0, stream>>>(alignedB, encB, wtin, b_in, wts,
      b_z, b_f0, b_f1, w_out, b_out, out);
}